// Round 2
// baseline (557.560 us; speedup 1.0000x reference)
//
#include <hip/hip_runtime.h>
#include <stdint.h>

#define B_ 4
#define C_ 128
#define H_ 240
#define W_ 240
#define HW_ (H_*W_)
#define NK_ 400
#define CELL_ 12
#define GW_ 20
#define EPS_ 1e-6f
#define LOG2E_ 1.4426950408889634f
#define NSPLIT 90
#define NCHUNK 10

typedef short bf16x8 __attribute__((ext_vector_type(8)));
typedef float f32x4 __attribute__((ext_vector_type(4)));

__device__ __forceinline__ float wave_sum64(float v){
#pragma unroll
  for (int o=32;o;o>>=1) v += __shfl_xor(v,o);
  return v;
}
__device__ __forceinline__ float wave_max64(float v){
#pragma unroll
  for (int o=32;o;o>>=1) v = fmaxf(v,__shfl_xor(v,o));
  return v;
}
__device__ __forceinline__ unsigned short f2bf(float f){
  uint32_t x = __float_as_uint(f);
  uint32_t r = (x + 0x7fffu + ((x>>16)&1u)) >> 16;
  return (unsigned short)r;
}
__device__ __forceinline__ void gl_lds16(const void* g, void* l){
  __builtin_amdgcn_global_load_lds((const __attribute__((address_space(1))) void*)g,
                                   (__attribute__((address_space(3))) void*)l, 16, 0, 0);
}

// ---------------- K0: zero accumulators ----------------
__global__ void k_zero(float* p, int n){
  int i = blockIdx.x*blockDim.x + threadIdx.x;
  if (i < n) p[i] = 0.f;
}

// ---------------- K1: spatial softmax keypoints ----------------
__global__ void k_kp(const float* __restrict__ loc, float* __restrict__ ps){
  int wid = (blockIdx.x*blockDim.x + threadIdx.x) >> 6;
  int l = threadIdx.x & 63;
  if (wid >= B_*NK_) return;
  int b = wid / NK_, n = wid % NK_;
  int gy = n / GW_, gx = n % GW_;
  const float* base = loc + (size_t)b*HW_ + (size_t)(gy*CELL_)*W_ + gx*CELL_;
  int d0 = l, d1 = l+64, d2 = l+128;
  float v0 = base[(d0/CELL_)*W_ + d0%CELL_];
  float v1 = base[(d1/CELL_)*W_ + d1%CELL_];
  float v2 = (l<16) ? base[(d2/CELL_)*W_ + d2%CELL_] : -3.4e38f;
  float m = wave_max64(fmaxf(fmaxf(v0,v1),v2));
  float e0 = expf(v0-m), e1 = expf(v1-m);
  float e2 = (l<16) ? expf(v2-m) : 0.f;
  float s  = e0+e1+e2;
  float sx = e0*(float)(d0%CELL_) + e1*(float)(d1%CELL_) + ((l<16)? e2*(float)(d2%CELL_) : 0.f);
  float sy = e0*(float)(d0/CELL_) + e1*(float)(d1/CELL_) + ((l<16)? e2*(float)(d2/CELL_) : 0.f);
  s = wave_sum64(s); sx = wave_sum64(sx); sy = wave_sum64(sy);
  if (l==0){
    // NOTE: reference's offs swaps grid axes: x-offset uses n//GW, y-offset uses n%GW
    ps[(size_t)wid*2+0] = sx/s + (float)((n/GW_)*CELL_);
    ps[(size_t)wid*2+1] = sy/s + (float)((n%GW_)*CELL_);
  }
}

// ---------------- bilinear helpers (exact reference semantics) ----------------
struct Bil { float wx, wy; int i00,i01,i10,i11; };
__device__ __forceinline__ Bil bilin(float px, float py){
  float x = fminf(fmaxf(px,0.f),(float)(W_-1));
  float y = fminf(fmaxf(py,0.f),(float)(H_-1));
  float x0f = floorf(x), y0f = floorf(y);
  Bil r; r.wx = x-x0f; r.wy = y-y0f;
  int x0 = (int)x0f, y0 = (int)y0f;
  int x1 = (x0+1 < W_) ? x0+1 : W_-1;
  int y1 = (y0+1 < H_) ? y0+1 : H_-1;
  r.i00 = y0*W_+x0; r.i01 = y0*W_+x1; r.i10 = y1*W_+x0; r.i11 = y1*W_+x1;
  return r;
}
__device__ __forceinline__ float bsample(const float* p, const Bil& bl){
  float v00=p[bl.i00], v01=p[bl.i01], v10=p[bl.i10], v11=p[bl.i11];
  return v00*(1.f-bl.wx)*(1.f-bl.wy) + v01*bl.wx*(1.f-bl.wy)
       + v10*(1.f-bl.wx)*bl.wy      + v11*bl.wx*bl.wy;
}

// ---------------- K2: ds = l2norm(bilinear(desc1, ps)); bf16 copy * LOG2E ----------------
__global__ void k_ds(const float* __restrict__ desc1, const float* __restrict__ ps,
                     float* __restrict__ dsF, unsigned short* __restrict__ dsA){
  int wid = (blockIdx.x*blockDim.x + threadIdx.x) >> 6;
  int l = threadIdx.x & 63;
  if (wid >= B_*NK_) return;
  int b = wid / NK_, n = wid % NK_;
  float px = ps[(size_t)wid*2+0], py = ps[(size_t)wid*2+1];
  Bil bl = bilin(px, py);
  const float* D = desc1 + (size_t)b*C_*HW_;
  float v[2];
#pragma unroll
  for (int t=0;t<2;t++){ int c = l + t*64; v[t] = bsample(D + (size_t)c*HW_, bl); }
  float nrm = wave_sum64(v[0]*v[0] + v[1]*v[1]);
  float inv = 1.f/(sqrtf(nrm)+EPS_);
#pragma unroll
  for (int t=0;t<2;t++){
    int c = l + t*64;
    float d = v[t]*inv;
    dsF[(size_t)wid*C_ + c] = d;
    dsA[((size_t)b*512 + n)*C_ + c] = f2bf(d*LOG2E_);
  }
}

// ---------------- K3: d2nT[b][m][c] = bf16(desc2[b][c][m] / (||row_w||+eps)) ----------------
__global__ __launch_bounds__(256) void k_d2nT(const float* __restrict__ desc2,
                                              unsigned short* __restrict__ d2nT){
  int b = blockIdx.x / H_;
  int h = blockIdx.x % H_;
  int w = threadIdx.x >> 6, l = threadIdx.x & 63;
  __shared__ unsigned short tile[C_*W_];   // [c][w], 61440 B
  const float* src = desc2 + (size_t)b*C_*HW_ + (size_t)h*W_;
#pragma unroll 1
  for (int i=0;i<32;i++){
    int c = w*32 + i;
    const float* row = src + (size_t)c*HW_;
    float4 v = make_float4(0.f,0.f,0.f,0.f);
    if (l < 60) v = *(const float4*)(row + l*4);
    float ss = v.x*v.x + v.y*v.y + v.z*v.z + v.w*v.w;
    ss = wave_sum64(ss);
    float inv = 1.f/(sqrtf(ss)+EPS_);
    if (l < 60){
      int o = c*W_ + l*4;
      ushort4 u; u.x=f2bf(v.x*inv); u.y=f2bf(v.y*inv); u.z=f2bf(v.z*inv); u.w=f2bf(v.w*inv);
      *(ushort4*)(&tile[o]) = u;
    }
  }
  __syncthreads();
  int wc = threadIdx.x;
  if (wc < W_){
    unsigned short* dst = d2nT + ((size_t)b*HW_ + (size_t)h*W_ + wc)*C_;
#pragma unroll 1
    for (int q=0;q<16;q++){
      uint32_t u[4];
#pragma unroll
      for (int p=0;p<4;p++){
        unsigned short lo = tile[(q*8+2*p  )*W_ + wc];
        unsigned short hi = tile[(q*8+2*p+1)*W_ + wc];
        u[p] = (uint32_t)lo | ((uint32_t)hi<<16);
      }
      *(uint4*)(dst + q*8) = make_uint4(u[0],u[1],u[2],u[3]);
    }
  }
}

// ---------------- K4: fused GEMM + online softmax-expectation ----------------
// grid: b(4) x mtile(4) x nsplit(90); block 256 (4 waves), wave = 32 rows x 64 cols/chunk
__global__ __launch_bounds__(256) void k_flash(const unsigned short* __restrict__ dsA,
                                               const unsigned short* __restrict__ d2nT,
                                               float* __restrict__ pdacc){
  int blk = blockIdx.x;
  int ns = blk % NSPLIT;
  int mt = (blk / NSPLIT) & 3;
  int b  = blk / (NSPLIT*4);
  int w = threadIdx.x >> 6, l = threadIdx.x & 63;
  __shared__ unsigned short Bt[2][64*128];   // 2 x 16 KB, [m][k] bf16, XOR-swizzled

  // A fragments: row = base + rf*16 + (l&15), k = s*32 + (l>>4)*8 + j
  bf16x8 a[2][4];
  const unsigned short* Ab = dsA + ((size_t)b*512 + (size_t)mt*128 + w*32)*C_;
#pragma unroll
  for (int rf=0;rf<2;rf++)
#pragma unroll
    for (int s=0;s<4;s++)
      a[rf][s] = *(const bf16x8*)(Ab + (rf*16 + (l&15))*C_ + s*32 + (l>>4)*8);

  float den[2][4], sy[2][4], sx[2][4];
#pragma unroll
  for (int rf=0;rf<2;rf++)
#pragma unroll
    for (int j=0;j<4;j++){ den[rf][j]=0.f; sy[rf][j]=0.f; sx[rf][j]=0.f; }

  const int mbase = ns*640;
  const char* tbase = (const char*)(d2nT + ((size_t)b*HW_ + (size_t)mbase)*C_);

  auto stage = [&](int ch, int bufi){
    const char* tb = tbase + (size_t)ch*64*256;
#pragma unroll
    for (int it=0; it<4; it++){
      int slab = w*4 + it;
      int m = slab*4 + (l>>4);
      int kb = (l&15)*16;
      int srcoff = m*256 + (kb ^ ((m&7)<<4));   // inverse-swizzled source (G4)
      gl_lds16(tb + srcoff, (char*)&Bt[bufi][0] + slab*1024 );
    }
  };

  stage(0,0);
  __syncthreads();
  int buf = 0;
  for (int ch=0; ch<NCHUNK; ch++){
    if (ch+1 < NCHUNK) stage(ch+1, buf^1);

    float yc[4], xc[4];
#pragma unroll
    for (int cf=0;cf<4;cf++){
      int mm = mbase + ch*64 + cf*16 + (l&15);
      int yq = mm / 240;
      yc[cf] = (float)yq;
      xc[cf] = (float)(mm - yq*240);
    }

    f32x4 acc[2][4];
#pragma unroll
    for (int rf=0;rf<2;rf++)
#pragma unroll
      for (int cf=0;cf<4;cf++){ f32x4 z = {0.f,0.f,0.f,0.f}; acc[rf][cf] = z; }

#pragma unroll
    for (int s=0;s<4;s++){
#pragma unroll
      for (int cf=0;cf<4;cf++){
        int row = cf*16 + (l&15);
        int kb = (s*64 + (l>>4)*16) ^ ((row&7)<<4);
        bf16x8 bv = *(const bf16x8*)((const char*)&Bt[buf][0] + row*256 + kb);
        acc[0][cf] = __builtin_amdgcn_mfma_f32_16x16x32_bf16(a[0][s], bv, acc[0][cf], 0,0,0);
        acc[1][cf] = __builtin_amdgcn_mfma_f32_16x16x32_bf16(a[1][s], bv, acc[1][cf], 0,0,0);
      }
    }

#pragma unroll
    for (int rf=0;rf<2;rf++)
#pragma unroll
      for (int cf=0;cf<4;cf++)
#pragma unroll
        for (int j=0;j<4;j++){
          float e = exp2f(acc[rf][cf][j]);   // ci already scaled by log2e
          den[rf][j] += e;
          sy[rf][j]  += e*yc[cf];
          sx[rf][j]  += e*xc[cf];
        }
    __syncthreads();
    buf ^= 1;
  }

  // reduce over the 16 lanes sharing each row (xor 1,2,4,8)
#pragma unroll
  for (int rf=0;rf<2;rf++)
#pragma unroll
    for (int j=0;j<4;j++){
#pragma unroll
      for (int o=1;o<16;o<<=1){
        den[rf][j] += __shfl_xor(den[rf][j], o);
        sy[rf][j]  += __shfl_xor(sy[rf][j], o);
        sx[rf][j]  += __shfl_xor(sx[rf][j], o);
      }
    }
  if ((l&15)==0){
    int rbase = mt*128 + w*32 + (l>>4)*4;
#pragma unroll
    for (int rf=0;rf<2;rf++)
#pragma unroll
      for (int j=0;j<4;j++){
        int row = rbase + rf*16 + j;
        if (row < NK_){
          float* p = pdacc + ((size_t)b*NK_ + row)*3;
          atomicAdd(p+0, den[rf][j]);
          atomicAdd(p+1, sy[rf][j]);
          atomicAdd(p+2, sx[rf][j]);
        }
      }
  }
}

// ---------------- K5: pd, dd, ss, sd, w_, per-batch moment reduction ----------------
__global__ void k_fin(const float* __restrict__ desc2, const float* __restrict__ sc1,
                      const float* __restrict__ sc2, const float* __restrict__ ps,
                      const float* __restrict__ dsF, const float* __restrict__ pdacc,
                      float* __restrict__ bsum){
  int wid = (blockIdx.x*blockDim.x + threadIdx.x) >> 6;
  int l = threadIdx.x & 63;
  if (wid >= B_*NK_) return;
  int b = wid / NK_;
  const float* pa = pdacc + (size_t)wid*3;
  float den = pa[0];
  float pdx = pa[1]/den;   // pd[...,0] = E[m//240], used as x in sampling (ref quirk)
  float pdy = pa[2]/den;
  Bil bl2 = bilin(pdx, pdy);
  const float* D2 = desc2 + (size_t)b*C_*HW_;
  float v[2];
#pragma unroll
  for (int t=0;t<2;t++){ int c = l + t*64; v[t] = bsample(D2 + (size_t)c*HW_, bl2); }
  float nrm = wave_sum64(v[0]*v[0] + v[1]*v[1]);
  float inv = 1.f/(sqrtf(nrm)+EPS_);
  float dot = 0.f;
#pragma unroll
  for (int t=0;t<2;t++){ int c = l + t*64; dot += dsF[(size_t)wid*C_ + c]*(v[t]*inv); }
  dot = wave_sum64(dot);
  float psx = ps[(size_t)wid*2+0], psy = ps[(size_t)wid*2+1];
  if (l==0){
    Bil bl1 = bilin(psx, psy);
    float ssv = bsample(sc1 + (size_t)b*HW_, bl1);
    float sdv = bsample(sc2 + (size_t)b*HW_, bl2);
    float wv = (dot + 1.f)*(ssv*sdv)*0.5f;
    float qsx = (psx - 119.5f)*0.25f, qsy = (119.5f - psy)*0.25f;
    float qdx = (pdx - 119.5f)*0.25f, qdy = (119.5f - pdy)*0.25f;
    float* S = bsum + b*12;
    atomicAdd(S+0, wv);
    atomicAdd(S+1, wv*qsx); atomicAdd(S+2, wv*qsy);
    atomicAdd(S+3, wv*qdx); atomicAdd(S+4, wv*qdy);
    atomicAdd(S+5, wv*qsx*qdx); atomicAdd(S+6, wv*qsx*qdy);
    atomicAdd(S+7, wv*qsy*qdx); atomicAdd(S+8, wv*qsy*qdy);
  }
}

// ---------------- K6: closed-form 2x2 Kabsch + loss ----------------
__global__ void k_pose(const float* __restrict__ bsum, const float* __restrict__ ptrn,
                       float* __restrict__ out){
  if (threadIdx.x != 0 || blockIdx.x != 0) return;
  float lt = 0.f, lr = 0.f;
  for (int b=0;b<B_;b++){
    const float* S = bsum + b*12;
    float Wv=S[0], A0=S[1], A1=S[2], Bv0=S[3], Bv1=S[4];
    float M00=S[5], M01=S[6], M10=S[7], M11=S[8];
    float wsum = Wv + EPS_;
    float qsx=A0/wsum, qsy=A1/wsum, qdx=Bv0/wsum, qdy=Bv1/wsum;
    float S00 = M00 - qsx*Bv0 - A0*qdx + Wv*qsx*qdx;
    float S01 = M01 - qsx*Bv1 - A0*qdy + Wv*qsx*qdy;
    float S10 = M10 - qsy*Bv0 - A1*qdx + Wv*qsy*qdx;
    float S11 = M11 - qsy*Bv1 - A1*qdy + Wv*qsy*qdy;
    // R = argmax_{SO(2)} tr(R S) == V diag(1,det(VU^T)) U^T from SVD(S)
    float sv = S01 - S10, cv = S00 + S11;
    float hyp = sqrtf(sv*sv + cv*cv);
    float cs = cv/hyp, sn = sv/hyp;
    float tx = qdx - (cs*qsx - sn*qsy);
    float ty = qdy - (sn*qsx + cs*qsy);
    const float* P = ptrn + b*9;
    float dtx = P[2]-tx, dty = P[5]-ty;
    lt += sqrtf(dtx*dtx + dty*dty);
    float a00 = P[0]*cs - P[1]*sn - 1.f;
    float a01 = P[0]*sn + P[1]*cs;
    float a10 = P[3]*cs - P[4]*sn;
    float a11 = P[3]*sn + P[4]*cs - 1.f;
    lr += sqrtf(a00*a00 + a01*a01 + a10*a10 + a11*a11);
  }
  out[0] = lt*0.25f + 10.f*(lr*0.25f);
}

// ---------------- launch ----------------
extern "C" void kernel_launch(void* const* d_in, const int* in_sizes, int n_in,
                              void* d_out, int out_size, void* d_ws, size_t ws_size,
                              hipStream_t stream){
  const float* loc1  = (const float*)d_in[0];
  const float* sc1   = (const float*)d_in[1];
  const float* desc1 = (const float*)d_in[2];
  const float* sc2   = (const float*)d_in[3];
  const float* desc2 = (const float*)d_in[4];
  const float* ptrn  = (const float*)d_in[5];
  float* out = (float*)d_out;

  char* ws = (char*)d_ws;
  float* pdacc = (float*)(ws + 0);                       // 4*400*3 f32 = 19200 B
  float* bsum  = (float*)(ws + 19200);                   // 48 f32
  float* ps    = (float*)(ws + 19456);                   // 4*400*2 f32
  float* dsF   = (float*)(ws + 32768);                   // 4*400*128 f32 = 819200 B
  unsigned short* dsA  = (unsigned short*)(ws + 851968); // 4*512*128 bf16 = 524288 B
  unsigned short* d2nT = (unsigned short*)(ws + 1376256);// 4*57600*128 bf16 = 58982400 B

  k_zero<<<(4848+255)/256, 256, 0, stream>>>(pdacc, 4848);
  k_kp  <<<400, 256, 0, stream>>>(loc1, ps);
  k_ds  <<<400, 256, 0, stream>>>(desc1, ps, dsF, dsA);
  k_d2nT<<<B_*H_, 256, 0, stream>>>(desc2, d2nT);
  k_flash<<<B_*4*NSPLIT, 256, 0, stream>>>(dsA, d2nT, pdacc);
  k_fin <<<400, 256, 0, stream>>>(desc2, sc1, sc2, ps, dsF, pdacc, bsum);
  k_pose<<<1, 64, 0, stream>>>(bsum, ptrn, out);
}

// Round 3
// 479.134 us; speedup vs baseline: 1.1637x; 1.1637x over previous
//
#include <hip/hip_runtime.h>
#include <stdint.h>

#define B_ 4
#define C_ 128
#define H_ 240
#define W_ 240
#define HW_ (H_*W_)
#define NK_ 400
#define CELL_ 12
#define GW_ 20
#define EPS_ 1e-6f
#define LOG2E_ 1.4426950408889634f
#define NSPLIT 90
#define NCHUNK 10

typedef short bf16x8 __attribute__((ext_vector_type(8)));
typedef float f32x4 __attribute__((ext_vector_type(4)));

__device__ __forceinline__ float wave_sum64(float v){
#pragma unroll
  for (int o=32;o;o>>=1) v += __shfl_xor(v,o);
  return v;
}
__device__ __forceinline__ float wave_max64(float v){
#pragma unroll
  for (int o=32;o;o>>=1) v = fmaxf(v,__shfl_xor(v,o));
  return v;
}
__device__ __forceinline__ unsigned short f2bf(float f){
  uint32_t x = __float_as_uint(f);
  uint32_t r = (x + 0x7fffu + ((x>>16)&1u)) >> 16;
  return (unsigned short)r;
}
__device__ __forceinline__ void gl_lds16(const void* g, void* l){
  __builtin_amdgcn_global_load_lds((const __attribute__((address_space(1))) void*)g,
                                   (__attribute__((address_space(3))) void*)l, 16, 0, 0);
}

// ---------------- K0: zero accumulators ----------------
__global__ void k_zero(float* p, int n){
  int i = blockIdx.x*blockDim.x + threadIdx.x;
  if (i < n) p[i] = 0.f;
}

// ---------------- K1: spatial softmax keypoints ----------------
__global__ void k_kp(const float* __restrict__ loc, float* __restrict__ ps){
  int wid = (blockIdx.x*blockDim.x + threadIdx.x) >> 6;
  int l = threadIdx.x & 63;
  if (wid >= B_*NK_) return;
  int b = wid / NK_, n = wid % NK_;
  int gy = n / GW_, gx = n % GW_;
  const float* base = loc + (size_t)b*HW_ + (size_t)(gy*CELL_)*W_ + gx*CELL_;
  int d0 = l, d1 = l+64, d2 = l+128;
  float v0 = base[(d0/CELL_)*W_ + d0%CELL_];
  float v1 = base[(d1/CELL_)*W_ + d1%CELL_];
  float v2 = (l<16) ? base[(d2/CELL_)*W_ + d2%CELL_] : -3.4e38f;
  float m = wave_max64(fmaxf(fmaxf(v0,v1),v2));
  float e0 = expf(v0-m), e1 = expf(v1-m);
  float e2 = (l<16) ? expf(v2-m) : 0.f;
  float s  = e0+e1+e2;
  float sx = e0*(float)(d0%CELL_) + e1*(float)(d1%CELL_) + ((l<16)? e2*(float)(d2%CELL_) : 0.f);
  float sy = e0*(float)(d0/CELL_) + e1*(float)(d1/CELL_) + ((l<16)? e2*(float)(d2/CELL_) : 0.f);
  s = wave_sum64(s); sx = wave_sum64(sx); sy = wave_sum64(sy);
  if (l==0){
    // NOTE: reference's offs swaps grid axes: x-offset uses n//GW, y-offset uses n%GW
    ps[(size_t)wid*2+0] = sx/s + (float)((n/GW_)*CELL_);
    ps[(size_t)wid*2+1] = sy/s + (float)((n%GW_)*CELL_);
  }
}

// ---------------- bilinear helpers (exact reference semantics) ----------------
struct Bil { float wx, wy; int i00,i01,i10,i11; };
__device__ __forceinline__ Bil bilin(float px, float py){
  float x = fminf(fmaxf(px,0.f),(float)(W_-1));
  float y = fminf(fmaxf(py,0.f),(float)(H_-1));
  float x0f = floorf(x), y0f = floorf(y);
  Bil r; r.wx = x-x0f; r.wy = y-y0f;
  int x0 = (int)x0f, y0 = (int)y0f;
  int x1 = (x0+1 < W_) ? x0+1 : W_-1;
  int y1 = (y0+1 < H_) ? y0+1 : H_-1;
  r.i00 = y0*W_+x0; r.i01 = y0*W_+x1; r.i10 = y1*W_+x0; r.i11 = y1*W_+x1;
  return r;
}
__device__ __forceinline__ float bsample(const float* p, const Bil& bl){
  float v00=p[bl.i00], v01=p[bl.i01], v10=p[bl.i10], v11=p[bl.i11];
  return v00*(1.f-bl.wx)*(1.f-bl.wy) + v01*bl.wx*(1.f-bl.wy)
       + v10*(1.f-bl.wx)*bl.wy      + v11*bl.wx*bl.wy;
}

// ---------------- K2: ds = l2norm(bilinear(desc1, ps)); bf16 copy * LOG2E ----------------
__global__ void k_ds(const float* __restrict__ desc1, const float* __restrict__ ps,
                     float* __restrict__ dsF, unsigned short* __restrict__ dsA){
  int wid = (blockIdx.x*blockDim.x + threadIdx.x) >> 6;
  int l = threadIdx.x & 63;
  if (wid >= B_*NK_) return;
  int b = wid / NK_, n = wid % NK_;
  float px = ps[(size_t)wid*2+0], py = ps[(size_t)wid*2+1];
  Bil bl = bilin(px, py);
  const float* D = desc1 + (size_t)b*C_*HW_;
  float v[2];
#pragma unroll
  for (int t=0;t<2;t++){ int c = l + t*64; v[t] = bsample(D + (size_t)c*HW_, bl); }
  float nrm = wave_sum64(v[0]*v[0] + v[1]*v[1]);
  float inv = 1.f/(sqrtf(nrm)+EPS_);
#pragma unroll
  for (int t=0;t<2;t++){
    int c = l + t*64;
    float d = v[t]*inv;
    dsF[(size_t)wid*C_ + c] = d;
    dsA[((size_t)b*512 + n)*C_ + c] = f2bf(d*LOG2E_);
  }
}

// ---------------- K3 v2: d2nT[b][m][c] = bf16(desc2[b][c][m] / (||row_w||+eps)) ----------------
// 64 channels per block (LDS 30 KB -> 5 blocks/CU), channel loop unrolled x8 for MLP.
__global__ __launch_bounds__(256) void k_d2nT(const float* __restrict__ desc2,
                                              unsigned short* __restrict__ d2nT){
  int blk = blockIdx.x;
  int chalf = blk & 1;
  int h = (blk >> 1) % H_;
  int b = blk / (2*H_);
  int w = threadIdx.x >> 6, l = threadIdx.x & 63;
  __shared__ unsigned short tile[64*W_];   // [c_local][w], 30720 B
  const float* src = desc2 + ((size_t)(b*C_ + chalf*64)*H_ + h)*W_;
#pragma unroll
  for (int i0=0;i0<16;i0+=8){
    float4 v[8];
#pragma unroll
    for (int u=0;u<8;u++){
      int cl = w*16 + i0 + u;
      v[u] = make_float4(0.f,0.f,0.f,0.f);
      if (l < 60) v[u] = *(const float4*)(src + (size_t)cl*HW_ + l*4);
    }
    float ss[8];
#pragma unroll
    for (int u=0;u<8;u++) ss[u] = v[u].x*v[u].x + v[u].y*v[u].y + v[u].z*v[u].z + v[u].w*v[u].w;
    // 8 independent 6-step butterfly reductions (compiler interleaves the chains)
#pragma unroll
    for (int o=32;o;o>>=1)
#pragma unroll
      for (int u=0;u<8;u++) ss[u] += __shfl_xor(ss[u], o);
#pragma unroll
    for (int u=0;u<8;u++){
      int cl = w*16 + i0 + u;
      float inv = 1.f/(sqrtf(ss[u])+EPS_);
      if (l < 60){
        ushort4 o4; o4.x=f2bf(v[u].x*inv); o4.y=f2bf(v[u].y*inv);
        o4.z=f2bf(v[u].z*inv); o4.w=f2bf(v[u].w*inv);
        *(ushort4*)(&tile[cl*W_ + l*4]) = o4;
      }
    }
  }
  __syncthreads();
  int t = threadIdx.x;
  if (t < W_){
    unsigned short* dst = d2nT + ((size_t)b*HW_ + (size_t)h*W_ + t)*C_ + chalf*64;
#pragma unroll
    for (int q=0;q<8;q++){
      uint32_t u[4];
#pragma unroll
      for (int p=0;p<4;p++){
        unsigned short lo = tile[(q*8+2*p  )*W_ + t];
        unsigned short hi = tile[(q*8+2*p+1)*W_ + t];
        u[p] = (uint32_t)lo | ((uint32_t)hi<<16);
      }
      *(uint4*)(dst + q*8) = make_uint4(u[0],u[1],u[2],u[3]);
    }
  }
}

// ---------------- K4: fused GEMM + online softmax-expectation ----------------
// grid: mt innermost (sibling blocks sharing a B-tile dispatched adjacently for L2/L3 reuse)
__global__ __launch_bounds__(256) void k_flash(const unsigned short* __restrict__ dsA,
                                               const unsigned short* __restrict__ d2nT,
                                               float* __restrict__ pdacc){
  int blk = blockIdx.x;
  int mt = blk & 3;
  int g  = blk >> 2;
  int ns = g % NSPLIT;
  int b  = g / NSPLIT;
  int w = threadIdx.x >> 6, l = threadIdx.x & 63;
  __shared__ unsigned short Bt[2][64*128];   // 2 x 16 KB, [m][k] bf16, XOR-swizzled

  // A fragments: row = base + rf*16 + (l&15), k = s*32 + (l>>4)*8 + j
  bf16x8 a[2][4];
  const unsigned short* Ab = dsA + ((size_t)b*512 + (size_t)mt*128 + w*32)*C_;
#pragma unroll
  for (int rf=0;rf<2;rf++)
#pragma unroll
    for (int s=0;s<4;s++)
      a[rf][s] = *(const bf16x8*)(Ab + (rf*16 + (l&15))*C_ + s*32 + (l>>4)*8);

  float den[2][4], sy[2][4], sx[2][4];
#pragma unroll
  for (int rf=0;rf<2;rf++)
#pragma unroll
    for (int j=0;j<4;j++){ den[rf][j]=0.f; sy[rf][j]=0.f; sx[rf][j]=0.f; }

  const int mbase = ns*640;
  const char* tbase = (const char*)(d2nT + ((size_t)b*HW_ + (size_t)mbase)*C_);

  auto stage = [&](int ch, int bufi){
    const char* tb = tbase + (size_t)ch*64*256;
#pragma unroll
    for (int it=0; it<4; it++){
      int slab = w*4 + it;
      int m = slab*4 + (l>>4);
      int kb = (l&15)*16;
      int srcoff = m*256 + (kb ^ ((m&7)<<4));   // inverse-swizzled source (G4)
      gl_lds16(tb + srcoff, (char*)&Bt[bufi][0] + slab*1024 );
    }
  };

  stage(0,0);
  __syncthreads();
  int buf = 0;
  for (int ch=0; ch<NCHUNK; ch++){
    if (ch+1 < NCHUNK) stage(ch+1, buf^1);

    float yc[4], xc[4];
#pragma unroll
    for (int cf=0;cf<4;cf++){
      int mm = mbase + ch*64 + cf*16 + (l&15);
      int yq = mm / 240;
      yc[cf] = (float)yq;
      xc[cf] = (float)(mm - yq*240);
    }

    f32x4 acc[2][4];
#pragma unroll
    for (int rf=0;rf<2;rf++)
#pragma unroll
      for (int cf=0;cf<4;cf++){ f32x4 z = {0.f,0.f,0.f,0.f}; acc[rf][cf] = z; }

#pragma unroll
    for (int s=0;s<4;s++){
#pragma unroll
      for (int cf=0;cf<4;cf++){
        int row = cf*16 + (l&15);
        int kb = (s*64 + (l>>4)*16) ^ ((row&7)<<4);
        bf16x8 bv = *(const bf16x8*)((const char*)&Bt[buf][0] + row*256 + kb);
        acc[0][cf] = __builtin_amdgcn_mfma_f32_16x16x32_bf16(a[0][s], bv, acc[0][cf], 0,0,0);
        acc[1][cf] = __builtin_amdgcn_mfma_f32_16x16x32_bf16(a[1][s], bv, acc[1][cf], 0,0,0);
      }
    }

#pragma unroll
    for (int rf=0;rf<2;rf++)
#pragma unroll
      for (int cf=0;cf<4;cf++)
#pragma unroll
        for (int j=0;j<4;j++){
          float e = exp2f(acc[rf][cf][j]);   // ci already scaled by log2e
          den[rf][j] += e;
          sy[rf][j]  += e*yc[cf];
          sx[rf][j]  += e*xc[cf];
        }
    __syncthreads();
    buf ^= 1;
  }

  // reduce over the 16 lanes sharing each row (xor 1,2,4,8)
#pragma unroll
  for (int rf=0;rf<2;rf++)
#pragma unroll
    for (int j=0;j<4;j++){
#pragma unroll
      for (int o=1;o<16;o<<=1){
        den[rf][j] += __shfl_xor(den[rf][j], o);
        sy[rf][j]  += __shfl_xor(sy[rf][j], o);
        sx[rf][j]  += __shfl_xor(sx[rf][j], o);
      }
    }
  if ((l&15)==0){
    int rbase = mt*128 + w*32 + (l>>4)*4;
#pragma unroll
    for (int rf=0;rf<2;rf++)
#pragma unroll
      for (int j=0;j<4;j++){
        int row = rbase + rf*16 + j;
        if (row < NK_){
          float* p = pdacc + ((size_t)b*NK_ + row)*3;
          atomicAdd(p+0, den[rf][j]);
          atomicAdd(p+1, sy[rf][j]);
          atomicAdd(p+2, sx[rf][j]);
        }
      }
  }
}

// ---------------- K5: pd, dd, ss, sd, w_, per-batch moment reduction ----------------
__global__ void k_fin(const float* __restrict__ desc2, const float* __restrict__ sc1,
                      const float* __restrict__ sc2, const float* __restrict__ ps,
                      const float* __restrict__ dsF, const float* __restrict__ pdacc,
                      float* __restrict__ bsum){
  int wid = (blockIdx.x*blockDim.x + threadIdx.x) >> 6;
  int l = threadIdx.x & 63;
  if (wid >= B_*NK_) return;
  int b = wid / NK_;
  const float* pa = pdacc + (size_t)wid*3;
  float den = pa[0];
  float pdx = pa[1]/den;   // pd[...,0] = E[m//240], used as x in sampling (ref quirk)
  float pdy = pa[2]/den;
  Bil bl2 = bilin(pdx, pdy);
  const float* D2 = desc2 + (size_t)b*C_*HW_;
  float v[2];
#pragma unroll
  for (int t=0;t<2;t++){ int c = l + t*64; v[t] = bsample(D2 + (size_t)c*HW_, bl2); }
  float nrm = wave_sum64(v[0]*v[0] + v[1]*v[1]);
  float inv = 1.f/(sqrtf(nrm)+EPS_);
  float dot = 0.f;
#pragma unroll
  for (int t=0;t<2;t++){ int c = l + t*64; dot += dsF[(size_t)wid*C_ + c]*(v[t]*inv); }
  dot = wave_sum64(dot);
  float psx = ps[(size_t)wid*2+0], psy = ps[(size_t)wid*2+1];
  if (l==0){
    Bil bl1 = bilin(psx, psy);
    float ssv = bsample(sc1 + (size_t)b*HW_, bl1);
    float sdv = bsample(sc2 + (size_t)b*HW_, bl2);
    float wv = (dot + 1.f)*(ssv*sdv)*0.5f;
    float qsx = (psx - 119.5f)*0.25f, qsy = (119.5f - psy)*0.25f;
    float qdx = (pdx - 119.5f)*0.25f, qdy = (119.5f - pdy)*0.25f;
    float* S = bsum + b*12;
    atomicAdd(S+0, wv);
    atomicAdd(S+1, wv*qsx); atomicAdd(S+2, wv*qsy);
    atomicAdd(S+3, wv*qdx); atomicAdd(S+4, wv*qdy);
    atomicAdd(S+5, wv*qsx*qdx); atomicAdd(S+6, wv*qsx*qdy);
    atomicAdd(S+7, wv*qsy*qdx); atomicAdd(S+8, wv*qsy*qdy);
  }
}

// ---------------- K6: closed-form 2x2 Kabsch + loss ----------------
__global__ void k_pose(const float* __restrict__ bsum, const float* __restrict__ ptrn,
                       float* __restrict__ out){
  if (threadIdx.x != 0 || blockIdx.x != 0) return;
  float lt = 0.f, lr = 0.f;
  for (int b=0;b<B_;b++){
    const float* S = bsum + b*12;
    float Wv=S[0], A0=S[1], A1=S[2], Bv0=S[3], Bv1=S[4];
    float M00=S[5], M01=S[6], M10=S[7], M11=S[8];
    float wsum = Wv + EPS_;
    float qsx=A0/wsum, qsy=A1/wsum, qdx=Bv0/wsum, qdy=Bv1/wsum;
    float S00 = M00 - qsx*Bv0 - A0*qdx + Wv*qsx*qdx;
    float S01 = M01 - qsx*Bv1 - A0*qdy + Wv*qsx*qdy;
    float S10 = M10 - qsy*Bv0 - A1*qdx + Wv*qsy*qdx;
    float S11 = M11 - qsy*Bv1 - A1*qdy + Wv*qsy*qdy;
    // R = argmax_{SO(2)} tr(R S) == V diag(1,det(VU^T)) U^T from SVD(S)
    float sv = S01 - S10, cv = S00 + S11;
    float hyp = sqrtf(sv*sv + cv*cv);
    float cs = cv/hyp, sn = sv/hyp;
    float tx = qdx - (cs*qsx - sn*qsy);
    float ty = qdy - (sn*qsx + cs*qsy);
    const float* P = ptrn + b*9;
    float dtx = P[2]-tx, dty = P[5]-ty;
    lt += sqrtf(dtx*dtx + dty*dty);
    float a00 = P[0]*cs - P[1]*sn - 1.f;
    float a01 = P[0]*sn + P[1]*cs;
    float a10 = P[3]*cs - P[4]*sn;
    float a11 = P[3]*sn + P[4]*cs - 1.f;
    lr += sqrtf(a00*a00 + a01*a01 + a10*a10 + a11*a11);
  }
  out[0] = lt*0.25f + 10.f*(lr*0.25f);
}

// ---------------- launch ----------------
extern "C" void kernel_launch(void* const* d_in, const int* in_sizes, int n_in,
                              void* d_out, int out_size, void* d_ws, size_t ws_size,
                              hipStream_t stream){
  const float* loc1  = (const float*)d_in[0];
  const float* sc1   = (const float*)d_in[1];
  const float* desc1 = (const float*)d_in[2];
  const float* sc2   = (const float*)d_in[3];
  const float* desc2 = (const float*)d_in[4];
  const float* ptrn  = (const float*)d_in[5];
  float* out = (float*)d_out;

  char* ws = (char*)d_ws;
  float* pdacc = (float*)(ws + 0);                       // 4*400*3 f32 = 19200 B
  float* bsum  = (float*)(ws + 19200);                   // 48 f32
  float* ps    = (float*)(ws + 19456);                   // 4*400*2 f32
  float* dsF   = (float*)(ws + 32768);                   // 4*400*128 f32 = 819200 B
  unsigned short* dsA  = (unsigned short*)(ws + 851968); // 4*512*128 bf16 = 524288 B
  unsigned short* d2nT = (unsigned short*)(ws + 1376256);// 4*57600*128 bf16 = 58982400 B

  k_zero<<<(4848+255)/256, 256, 0, stream>>>(pdacc, 4848);
  k_kp  <<<400, 256, 0, stream>>>(loc1, ps);
  k_ds  <<<400, 256, 0, stream>>>(desc1, ps, dsF, dsA);
  k_d2nT<<<B_*H_*2, 256, 0, stream>>>(desc2, d2nT);
  k_flash<<<B_*4*NSPLIT, 256, 0, stream>>>(dsA, d2nT, pdacc);
  k_fin <<<400, 256, 0, stream>>>(desc2, sc1, sc2, ps, dsF, pdacc, bsum);
  k_pose<<<1, 64, 0, stream>>>(bsum, ptrn, out);
}

// Round 4
// 460.586 us; speedup vs baseline: 1.2105x; 1.0403x over previous
//
#include <hip/hip_runtime.h>
#include <stdint.h>

#define B_ 4
#define C_ 128
#define H_ 240
#define W_ 240
#define HW_ (H_*W_)
#define NK_ 400
#define CELL_ 12
#define GW_ 20
#define EPS_ 1e-6f
#define LOG2E_ 1.4426950408889634f
#define NB2 18           // ns-blocks per (b,mt): 57600/18 = 3200 m per block
#define MT2 7            // 7 m-tiles of 64 rows cover 448 >= 400

typedef short bf16x8 __attribute__((ext_vector_type(8)));
typedef float f32x4 __attribute__((ext_vector_type(4)));

__device__ __forceinline__ float wave_sum64(float v){
#pragma unroll
  for (int o=32;o;o>>=1) v += __shfl_xor(v,o);
  return v;
}
__device__ __forceinline__ float wave_max64(float v){
#pragma unroll
  for (int o=32;o;o>>=1) v = fmaxf(v,__shfl_xor(v,o));
  return v;
}
__device__ __forceinline__ unsigned short f2bf(float f){
  uint32_t x = __float_as_uint(f);
  uint32_t r = (x + 0x7fffu + ((x>>16)&1u)) >> 16;
  return (unsigned short)r;
}

// ---------------- K0: zero accumulators ----------------
__global__ void k_zero(float* p, int n){
  int i = blockIdx.x*blockDim.x + threadIdx.x;
  if (i < n) p[i] = 0.f;
}

// ---------------- K1: spatial softmax keypoints ----------------
__global__ void k_kp(const float* __restrict__ loc, float* __restrict__ ps){
  int wid = (blockIdx.x*blockDim.x + threadIdx.x) >> 6;
  int l = threadIdx.x & 63;
  if (wid >= B_*NK_) return;
  int b = wid / NK_, n = wid % NK_;
  int gy = n / GW_, gx = n % GW_;
  const float* base = loc + (size_t)b*HW_ + (size_t)(gy*CELL_)*W_ + gx*CELL_;
  int d0 = l, d1 = l+64, d2 = l+128;
  float v0 = base[(d0/CELL_)*W_ + d0%CELL_];
  float v1 = base[(d1/CELL_)*W_ + d1%CELL_];
  float v2 = (l<16) ? base[(d2/CELL_)*W_ + d2%CELL_] : -3.4e38f;
  float m = wave_max64(fmaxf(fmaxf(v0,v1),v2));
  float e0 = expf(v0-m), e1 = expf(v1-m);
  float e2 = (l<16) ? expf(v2-m) : 0.f;
  float s  = e0+e1+e2;
  float sx = e0*(float)(d0%CELL_) + e1*(float)(d1%CELL_) + ((l<16)? e2*(float)(d2%CELL_) : 0.f);
  float sy = e0*(float)(d0/CELL_) + e1*(float)(d1/CELL_) + ((l<16)? e2*(float)(d2/CELL_) : 0.f);
  s = wave_sum64(s); sx = wave_sum64(sx); sy = wave_sum64(sy);
  if (l==0){
    // NOTE: reference's offs swaps grid axes: x-offset uses n//GW, y-offset uses n%GW
    ps[(size_t)wid*2+0] = sx/s + (float)((n/GW_)*CELL_);
    ps[(size_t)wid*2+1] = sy/s + (float)((n%GW_)*CELL_);
  }
}

// ---------------- bilinear helpers (exact reference semantics) ----------------
struct Bil { float wx, wy; int i00,i01,i10,i11; };
__device__ __forceinline__ Bil bilin(float px, float py){
  float x = fminf(fmaxf(px,0.f),(float)(W_-1));
  float y = fminf(fmaxf(py,0.f),(float)(H_-1));
  float x0f = floorf(x), y0f = floorf(y);
  Bil r; r.wx = x-x0f; r.wy = y-y0f;
  int x0 = (int)x0f, y0 = (int)y0f;
  int x1 = (x0+1 < W_) ? x0+1 : W_-1;
  int y1 = (y0+1 < H_) ? y0+1 : H_-1;
  r.i00 = y0*W_+x0; r.i01 = y0*W_+x1; r.i10 = y1*W_+x0; r.i11 = y1*W_+x1;
  return r;
}
__device__ __forceinline__ float bsample(const float* p, const Bil& bl){
  float v00=p[bl.i00], v01=p[bl.i01], v10=p[bl.i10], v11=p[bl.i11];
  return v00*(1.f-bl.wx)*(1.f-bl.wy) + v01*bl.wx*(1.f-bl.wy)
       + v10*(1.f-bl.wx)*bl.wy      + v11*bl.wx*bl.wy;
}

// ---------------- K2: ds = l2norm(bilinear(desc1, ps)); bf16 copy * LOG2E ----------------
__global__ void k_ds(const float* __restrict__ desc1, const float* __restrict__ ps,
                     float* __restrict__ dsF, unsigned short* __restrict__ dsA){
  int wid = (blockIdx.x*blockDim.x + threadIdx.x) >> 6;
  int l = threadIdx.x & 63;
  if (wid >= B_*NK_) return;
  int b = wid / NK_, n = wid % NK_;
  float px = ps[(size_t)wid*2+0], py = ps[(size_t)wid*2+1];
  Bil bl = bilin(px, py);
  const float* D = desc1 + (size_t)b*C_*HW_;
  float v[2];
#pragma unroll
  for (int t=0;t<2;t++){ int c = l + t*64; v[t] = bsample(D + (size_t)c*HW_, bl); }
  float nrm = wave_sum64(v[0]*v[0] + v[1]*v[1]);
  float inv = 1.f/(sqrtf(nrm)+EPS_);
#pragma unroll
  for (int t=0;t<2;t++){
    int c = l + t*64;
    float d = v[t]*inv;
    dsF[(size_t)wid*C_ + c] = d;
    dsA[((size_t)b*512 + n)*C_ + c] = f2bf(d*LOG2E_);
  }
}

// ---------------- K3: d2nT[b][m][c] = bf16(desc2[b][c][m] / (||row_w||+eps)) ----------------
// 64 channels per block (LDS 30 KB -> 5 blocks/CU), channel loop unrolled x8 for MLP.
__global__ __launch_bounds__(256) void k_d2nT(const float* __restrict__ desc2,
                                              unsigned short* __restrict__ d2nT){
  int blk = blockIdx.x;
  int chalf = blk & 1;
  int h = (blk >> 1) % H_;
  int b = blk / (2*H_);
  int w = threadIdx.x >> 6, l = threadIdx.x & 63;
  __shared__ unsigned short tile[64*W_];   // [c_local][w], 30720 B
  const float* src = desc2 + ((size_t)(b*C_ + chalf*64)*H_ + h)*W_;
#pragma unroll
  for (int i0=0;i0<16;i0+=8){
    float4 v[8];
#pragma unroll
    for (int u=0;u<8;u++){
      int cl = w*16 + i0 + u;
      v[u] = make_float4(0.f,0.f,0.f,0.f);
      if (l < 60) v[u] = *(const float4*)(src + (size_t)cl*HW_ + l*4);
    }
    float ss[8];
#pragma unroll
    for (int u=0;u<8;u++) ss[u] = v[u].x*v[u].x + v[u].y*v[u].y + v[u].z*v[u].z + v[u].w*v[u].w;
#pragma unroll
    for (int o=32;o;o>>=1)
#pragma unroll
      for (int u=0;u<8;u++) ss[u] += __shfl_xor(ss[u], o);
#pragma unroll
    for (int u=0;u<8;u++){
      int cl = w*16 + i0 + u;
      float inv = 1.f/(sqrtf(ss[u])+EPS_);
      if (l < 60){
        ushort4 o4; o4.x=f2bf(v[u].x*inv); o4.y=f2bf(v[u].y*inv);
        o4.z=f2bf(v[u].z*inv); o4.w=f2bf(v[u].w*inv);
        *(ushort4*)(&tile[cl*W_ + l*4]) = o4;
      }
    }
  }
  __syncthreads();
  int t = threadIdx.x;
  if (t < W_){
    unsigned short* dst = d2nT + ((size_t)b*HW_ + (size_t)h*W_ + t)*C_ + chalf*64;
#pragma unroll
    for (int q=0;q<8;q++){
      uint32_t u[4];
#pragma unroll
      for (int p=0;p<4;p++){
        unsigned short lo = tile[(q*8+2*p  )*W_ + t];
        unsigned short hi = tile[(q*8+2*p+1)*W_ + t];
        u[p] = (uint32_t)lo | ((uint32_t)hi<<16);
      }
      *(uint4*)(dst + q*8) = make_uint4(u[0],u[1],u[2],u[3]);
    }
  }
}

// ---------------- K4 v3: fused GEMM + online softmax-expectation, LDS-free ----------------
// B-fragments gathered directly from d2nT (per-lane global_load_dwordx4, 16 full cache
// lines per instr). No barriers, no LDS; per-wave double-buffered prefetch (bA/bB).
// Wave owns 64 A-rows (rf=0..3); waves of a block split the 3200-m range (chunks of 32,
// stride 128). Grid: mt innermost so 7 sibling blocks share the B-panel via L2.
__global__ __launch_bounds__(256, 2) void k_flash(const unsigned short* __restrict__ dsA,
                                                  const unsigned short* __restrict__ d2nT,
                                                  float* __restrict__ pdacc){
  int blk = blockIdx.x;
  int mt = blk % MT2;
  int g  = blk / MT2;
  int nb = g % NB2;
  int b  = g / NB2;
  int w = threadIdx.x >> 6, l = threadIdx.x & 63;

  // A fragments: row = mt*64 + rf*16 + (l&15), k = s*32 + (l>>4)*8 + j
  bf16x8 a[4][4];
  const unsigned short* Ab = dsA + ((size_t)b*512 + (size_t)mt*64)*C_;
#pragma unroll
  for (int rf=0;rf<4;rf++)
#pragma unroll
    for (int s=0;s<4;s++)
      a[rf][s] = *(const bf16x8*)(Ab + (rf*16 + (l&15))*C_ + s*32 + (l>>4)*8);

  float den[4][4], sy[4][4], sx[4][4];
#pragma unroll
  for (int rf=0;rf<4;rf++)
#pragma unroll
    for (int j=0;j<4;j++){ den[rf][j]=0.f; sy[rf][j]=0.f; sx[rf][j]=0.f; }

  const unsigned short* Bb = d2nT + (size_t)b*HW_*C_ + ((size_t)(l&15))*C_ + (l>>4)*8;
  const int mc0 = nb*3200 + w*32;
  const int end = nb*3200 + 3200;

  auto loadB = [&](bf16x8 (&bf)[4][2], int mc){
#pragma unroll
    for (int s=0;s<4;s++)
#pragma unroll
      for (int cf=0;cf<2;cf++)
        bf[s][cf] = *(const bf16x8*)(Bb + (size_t)(mc + cf*16)*C_ + s*32);
  };

  auto compute = [&](bf16x8 (&bf)[4][2], int mc){
    f32x4 acc[4][2];
#pragma unroll
    for (int rf=0;rf<4;rf++)
#pragma unroll
      for (int cf=0;cf<2;cf++){ f32x4 z = {0.f,0.f,0.f,0.f}; acc[rf][cf] = z; }
#pragma unroll
    for (int s=0;s<4;s++)
#pragma unroll
      for (int cf=0;cf<2;cf++)
#pragma unroll
        for (int rf=0;rf<4;rf++)
          acc[rf][cf] = __builtin_amdgcn_mfma_f32_16x16x32_bf16(a[rf][s], bf[s][cf], acc[rf][cf], 0,0,0);
#pragma unroll
    for (int cf=0;cf<2;cf++){
      int mm = mc + cf*16 + (l&15);
      int yq = mm / 240;
      float yc = (float)yq, xc = (float)(mm - yq*240);
#pragma unroll
      for (int rf=0;rf<4;rf++)
#pragma unroll
        for (int j=0;j<4;j++){
          float e = exp2f(acc[rf][cf][j]);   // ci pre-scaled by log2e in dsA
          den[rf][j] += e;
          sy[rf][j]  += e*yc;
          sx[rf][j]  += e*xc;
        }
    }
  };

  bf16x8 bA[4][2], bB[4][2];
  loadB(bA, mc0);
#pragma unroll 1
  for (int mc = mc0; mc < end; mc += 256){
    if (mc+128 < end) loadB(bB, mc+128);
    compute(bA, mc);
    if (mc+128 < end){
      if (mc+256 < end) loadB(bA, mc+256);
      compute(bB, mc+128);
    }
  }

  // reduce over the 16 lanes sharing each row (xor 1,2,4,8)
#pragma unroll
  for (int rf=0;rf<4;rf++)
#pragma unroll
    for (int j=0;j<4;j++){
#pragma unroll
      for (int o=1;o<16;o<<=1){
        den[rf][j] += __shfl_xor(den[rf][j], o);
        sy[rf][j]  += __shfl_xor(sy[rf][j], o);
        sx[rf][j]  += __shfl_xor(sx[rf][j], o);
      }
    }
  if ((l&15)==0){
    int rbase = mt*64 + (l>>4)*4;
#pragma unroll
    for (int rf=0;rf<4;rf++)
#pragma unroll
      for (int j=0;j<4;j++){
        int row = rbase + rf*16 + j;
        if (row < NK_){
          float* p = pdacc + ((size_t)b*NK_ + row)*3;
          atomicAdd(p+0, den[rf][j]);
          atomicAdd(p+1, sy[rf][j]);
          atomicAdd(p+2, sx[rf][j]);
        }
      }
  }
}

// ---------------- K5: pd, dd, ss, sd, w_, per-batch moment reduction ----------------
__global__ void k_fin(const float* __restrict__ desc2, const float* __restrict__ sc1,
                      const float* __restrict__ sc2, const float* __restrict__ ps,
                      const float* __restrict__ dsF, const float* __restrict__ pdacc,
                      float* __restrict__ bsum){
  int wid = (blockIdx.x*blockDim.x + threadIdx.x) >> 6;
  int l = threadIdx.x & 63;
  if (wid >= B_*NK_) return;
  int b = wid / NK_;
  const float* pa = pdacc + (size_t)wid*3;
  float den = pa[0];
  float pdx = pa[1]/den;   // pd[...,0] = E[m//240], used as x in sampling (ref quirk)
  float pdy = pa[2]/den;
  Bil bl2 = bilin(pdx, pdy);
  const float* D2 = desc2 + (size_t)b*C_*HW_;
  float v[2];
#pragma unroll
  for (int t=0;t<2;t++){ int c = l + t*64; v[t] = bsample(D2 + (size_t)c*HW_, bl2); }
  float nrm = wave_sum64(v[0]*v[0] + v[1]*v[1]);
  float inv = 1.f/(sqrtf(nrm)+EPS_);
  float dot = 0.f;
#pragma unroll
  for (int t=0;t<2;t++){ int c = l + t*64; dot += dsF[(size_t)wid*C_ + c]*(v[t]*inv); }
  dot = wave_sum64(dot);
  float psx = ps[(size_t)wid*2+0], psy = ps[(size_t)wid*2+1];
  if (l==0){
    Bil bl1 = bilin(psx, psy);
    float ssv = bsample(sc1 + (size_t)b*HW_, bl1);
    float sdv = bsample(sc2 + (size_t)b*HW_, bl2);
    float wv = (dot + 1.f)*(ssv*sdv)*0.5f;
    float qsx = (psx - 119.5f)*0.25f, qsy = (119.5f - psy)*0.25f;
    float qdx = (pdx - 119.5f)*0.25f, qdy = (119.5f - pdy)*0.25f;
    float* S = bsum + b*12;
    atomicAdd(S+0, wv);
    atomicAdd(S+1, wv*qsx); atomicAdd(S+2, wv*qsy);
    atomicAdd(S+3, wv*qdx); atomicAdd(S+4, wv*qdy);
    atomicAdd(S+5, wv*qsx*qdx); atomicAdd(S+6, wv*qsx*qdy);
    atomicAdd(S+7, wv*qsy*qdx); atomicAdd(S+8, wv*qsy*qdy);
  }
}

// ---------------- K6: closed-form 2x2 Kabsch + loss ----------------
__global__ void k_pose(const float* __restrict__ bsum, const float* __restrict__ ptrn,
                       float* __restrict__ out){
  if (threadIdx.x != 0 || blockIdx.x != 0) return;
  float lt = 0.f, lr = 0.f;
  for (int b=0;b<B_;b++){
    const float* S = bsum + b*12;
    float Wv=S[0], A0=S[1], A1=S[2], Bv0=S[3], Bv1=S[4];
    float M00=S[5], M01=S[6], M10=S[7], M11=S[8];
    float wsum = Wv + EPS_;
    float qsx=A0/wsum, qsy=A1/wsum, qdx=Bv0/wsum, qdy=Bv1/wsum;
    float S00 = M00 - qsx*Bv0 - A0*qdx + Wv*qsx*qdx;
    float S01 = M01 - qsx*Bv1 - A0*qdy + Wv*qsx*qdy;
    float S10 = M10 - qsy*Bv0 - A1*qdx + Wv*qsy*qdx;
    float S11 = M11 - qsy*Bv1 - A1*qdy + Wv*qsy*qdy;
    // R = argmax_{SO(2)} tr(R S) == V diag(1,det(VU^T)) U^T from SVD(S)
    float sv = S01 - S10, cv = S00 + S11;
    float hyp = sqrtf(sv*sv + cv*cv);
    float cs = cv/hyp, sn = sv/hyp;
    float tx = qdx - (cs*qsx - sn*qsy);
    float ty = qdy - (sn*qsx + cs*qsy);
    const float* P = ptrn + b*9;
    float dtx = P[2]-tx, dty = P[5]-ty;
    lt += sqrtf(dtx*dtx + dty*dty);
    float a00 = P[0]*cs - P[1]*sn - 1.f;
    float a01 = P[0]*sn + P[1]*cs;
    float a10 = P[3]*cs - P[4]*sn;
    float a11 = P[3]*sn + P[4]*cs - 1.f;
    lr += sqrtf(a00*a00 + a01*a01 + a10*a10 + a11*a11);
  }
  out[0] = lt*0.25f + 10.f*(lr*0.25f);
}

// ---------------- launch ----------------
extern "C" void kernel_launch(void* const* d_in, const int* in_sizes, int n_in,
                              void* d_out, int out_size, void* d_ws, size_t ws_size,
                              hipStream_t stream){
  const float* loc1  = (const float*)d_in[0];
  const float* sc1   = (const float*)d_in[1];
  const float* desc1 = (const float*)d_in[2];
  const float* sc2   = (const float*)d_in[3];
  const float* desc2 = (const float*)d_in[4];
  const float* ptrn  = (const float*)d_in[5];
  float* out = (float*)d_out;

  char* ws = (char*)d_ws;
  float* pdacc = (float*)(ws + 0);                       // 4*400*3 f32 = 19200 B
  float* bsum  = (float*)(ws + 19200);                   // 48 f32
  float* ps    = (float*)(ws + 19456);                   // 4*400*2 f32
  float* dsF   = (float*)(ws + 32768);                   // 4*400*128 f32 = 819200 B
  unsigned short* dsA  = (unsigned short*)(ws + 851968); // 4*512*128 bf16 = 524288 B
  unsigned short* d2nT = (unsigned short*)(ws + 1376256);// 4*57600*128 bf16 = 58982400 B

  k_zero<<<(4848+255)/256, 256, 0, stream>>>(pdacc, 4848);
  k_kp  <<<400, 256, 0, stream>>>(loc1, ps);
  k_ds  <<<400, 256, 0, stream>>>(desc1, ps, dsF, dsA);
  k_d2nT<<<B_*H_*2, 256, 0, stream>>>(desc2, d2nT);
  k_flash<<<B_*NB2*MT2, 256, 0, stream>>>(dsA, d2nT, pdacc);
  k_fin <<<400, 256, 0, stream>>>(desc2, sc1, sc2, ps, dsF, pdacc, bsum);
  k_pose<<<1, 64, 0, stream>>>(bsum, ptrn, out);
}

// Round 10
// 362.504 us; speedup vs baseline: 1.5381x; 1.2706x over previous
//
#include <hip/hip_runtime.h>
#include <stdint.h>

#define B_ 4
#define C_ 128
#define H_ 240
#define W_ 240
#define HW_ (H_*W_)
#define NK_ 400
#define CELL_ 12
#define GW_ 20
#define EPS_ 1e-6f
#define LOG2E_ 1.4426950408889634f
#define NB2 18           // ns-blocks per (b,mt): 57600/18 = 3200 m per block
#define MT2 7            // 7 m-tiles of 64 rows cover 448 >= 400

typedef short bf16x8 __attribute__((ext_vector_type(8)));
typedef float f32x4 __attribute__((ext_vector_type(4)));

__device__ __forceinline__ float wave_sum64(float v){
#pragma unroll
  for (int o=32;o;o>>=1) v += __shfl_xor(v,o);
  return v;
}
__device__ __forceinline__ float wave_max64(float v){
#pragma unroll
  for (int o=32;o;o>>=1) v = fmaxf(v,__shfl_xor(v,o));
  return v;
}
__device__ __forceinline__ unsigned short f2bf(float f){
  uint32_t x = __float_as_uint(f);
  uint32_t r = (x + 0x7fffu + ((x>>16)&1u)) >> 16;
  return (unsigned short)r;
}

// ---------------- K0: zero accumulators ----------------
__global__ void k_zero(float* p, int n){
  int i = blockIdx.x*blockDim.x + threadIdx.x;
  if (i < n) p[i] = 0.f;
}

// ---------------- K1: spatial softmax keypoints ----------------
__global__ void k_kp(const float* __restrict__ loc, float* __restrict__ ps){
  int wid = (blockIdx.x*blockDim.x + threadIdx.x) >> 6;
  int l = threadIdx.x & 63;
  if (wid >= B_*NK_) return;
  int b = wid / NK_, n = wid % NK_;
  int gy = n / GW_, gx = n % GW_;
  const float* base = loc + (size_t)b*HW_ + (size_t)(gy*CELL_)*W_ + gx*CELL_;
  int d0 = l, d1 = l+64, d2 = l+128;
  float v0 = base[(d0/CELL_)*W_ + d0%CELL_];
  float v1 = base[(d1/CELL_)*W_ + d1%CELL_];
  float v2 = (l<16) ? base[(d2/CELL_)*W_ + d2%CELL_] : -3.4e38f;
  float m = wave_max64(fmaxf(fmaxf(v0,v1),v2));
  float e0 = expf(v0-m), e1 = expf(v1-m);
  float e2 = (l<16) ? expf(v2-m) : 0.f;
  float s  = e0+e1+e2;
  float sx = e0*(float)(d0%CELL_) + e1*(float)(d1%CELL_) + ((l<16)? e2*(float)(d2%CELL_) : 0.f);
  float sy = e0*(float)(d0/CELL_) + e1*(float)(d1/CELL_) + ((l<16)? e2*(float)(d2/CELL_) : 0.f);
  s = wave_sum64(s); sx = wave_sum64(sx); sy = wave_sum64(sy);
  if (l==0){
    // NOTE: reference's offs swaps grid axes: x-offset uses n//GW, y-offset uses n%GW
    ps[(size_t)wid*2+0] = sx/s + (float)((n/GW_)*CELL_);
    ps[(size_t)wid*2+1] = sy/s + (float)((n%GW_)*CELL_);
  }
}

// ---------------- bilinear helpers (exact reference semantics) ----------------
struct Bil { float wx, wy; int i00,i01,i10,i11; };
__device__ __forceinline__ Bil bilin(float px, float py){
  float x = fminf(fmaxf(px,0.f),(float)(W_-1));
  float y = fminf(fmaxf(py,0.f),(float)(H_-1));
  float x0f = floorf(x), y0f = floorf(y);
  Bil r; r.wx = x-x0f; r.wy = y-y0f;
  int x0 = (int)x0f, y0 = (int)y0f;
  int x1 = (x0+1 < W_) ? x0+1 : W_-1;
  int y1 = (y0+1 < H_) ? y0+1 : H_-1;
  r.i00 = y0*W_+x0; r.i01 = y0*W_+x1; r.i10 = y1*W_+x0; r.i11 = y1*W_+x1;
  return r;
}
__device__ __forceinline__ float bsample(const float* p, const Bil& bl){
  float v00=p[bl.i00], v01=p[bl.i01], v10=p[bl.i10], v11=p[bl.i11];
  return v00*(1.f-bl.wx)*(1.f-bl.wy) + v01*bl.wx*(1.f-bl.wy)
       + v10*(1.f-bl.wx)*bl.wy      + v11*bl.wx*bl.wy;
}

// ---------------- K2: ds = l2norm(bilinear(desc1, ps)); bf16 copy * LOG2E ----------------
__global__ void k_ds(const float* __restrict__ desc1, const float* __restrict__ ps,
                     float* __restrict__ dsF, unsigned short* __restrict__ dsA){
  int wid = (blockIdx.x*blockDim.x + threadIdx.x) >> 6;
  int l = threadIdx.x & 63;
  if (wid >= B_*NK_) return;
  int b = wid / NK_, n = wid % NK_;
  float px = ps[(size_t)wid*2+0], py = ps[(size_t)wid*2+1];
  Bil bl = bilin(px, py);
  const float* D = desc1 + (size_t)b*C_*HW_;
  float v[2];
#pragma unroll
  for (int t=0;t<2;t++){ int c = l + t*64; v[t] = bsample(D + (size_t)c*HW_, bl); }
  float nrm = wave_sum64(v[0]*v[0] + v[1]*v[1]);
  float inv = 1.f/(sqrtf(nrm)+EPS_);
#pragma unroll
  for (int t=0;t<2;t++){
    int c = l + t*64;
    float d = v[t]*inv;
    dsF[(size_t)wid*C_ + c] = d;
    dsA[((size_t)b*512 + n)*C_ + c] = f2bf(d*LOG2E_);
  }
}

// ---------------- K3: d2nT[b][m][c] = bf16(desc2[b][c][m] / (||row_w||+eps)) ----------------
// 64 channels per block (LDS 30 KB -> 5 blocks/CU), channel loop unrolled x8 for MLP.
__global__ __launch_bounds__(256) void k_d2nT(const float* __restrict__ desc2,
                                              unsigned short* __restrict__ d2nT){
  int blk = blockIdx.x;
  int chalf = blk & 1;
  int h = (blk >> 1) % H_;
  int b = blk / (2*H_);
  int w = threadIdx.x >> 6, l = threadIdx.x & 63;
  __shared__ unsigned short tile[64*W_];   // [c_local][w], 30720 B
  const float* src = desc2 + ((size_t)(b*C_ + chalf*64)*H_ + h)*W_;
#pragma unroll
  for (int i0=0;i0<16;i0+=8){
    float4 v[8];
#pragma unroll
    for (int u=0;u<8;u++){
      int cl = w*16 + i0 + u;
      v[u] = make_float4(0.f,0.f,0.f,0.f);
      if (l < 60) v[u] = *(const float4*)(src + (size_t)cl*HW_ + l*4);
    }
    float ss[8];
#pragma unroll
    for (int u=0;u<8;u++) ss[u] = v[u].x*v[u].x + v[u].y*v[u].y + v[u].z*v[u].z + v[u].w*v[u].w;
#pragma unroll
    for (int o=32;o;o>>=1)
#pragma unroll
      for (int u=0;u<8;u++) ss[u] += __shfl_xor(ss[u], o);
#pragma unroll
    for (int u=0;u<8;u++){
      int cl = w*16 + i0 + u;
      float inv = 1.f/(sqrtf(ss[u])+EPS_);
      if (l < 60){
        ushort4 o4; o4.x=f2bf(v[u].x*inv); o4.y=f2bf(v[u].y*inv);
        o4.z=f2bf(v[u].z*inv); o4.w=f2bf(v[u].w*inv);
        *(ushort4*)(&tile[cl*W_ + l*4]) = o4;
      }
    }
  }
  __syncthreads();
  int t = threadIdx.x;
  if (t < W_){
    unsigned short* dst = d2nT + ((size_t)b*HW_ + (size_t)h*W_ + t)*C_ + chalf*64;
#pragma unroll
    for (int q=0;q<8;q++){
      uint32_t u[4];
#pragma unroll
      for (int p=0;p<4;p++){
        unsigned short lo = tile[(q*8+2*p  )*W_ + t];
        unsigned short hi = tile[(q*8+2*p+1)*W_ + t];
        u[p] = (uint32_t)lo | ((uint32_t)hi<<16);
      }
      *(uint4*)(dst + q*8) = make_uint4(u[0],u[1],u[2],u[3]);
    }
  }
}

// ---------------- K4: fused GEMM + online softmax-expectation, LDS-free ----------------
__global__ __launch_bounds__(256, 2) void k_flash(const unsigned short* __restrict__ dsA,
                                                  const unsigned short* __restrict__ d2nT,
                                                  float* __restrict__ pdacc){
  int blk = blockIdx.x;
  int mt = blk % MT2;
  int g  = blk / MT2;
  int nb = g % NB2;
  int b  = g / NB2;
  int w = threadIdx.x >> 6, l = threadIdx.x & 63;

  // A fragments: row = mt*64 + rf*16 + (l&15), k = s*32 + (l>>4)*8 + j
  bf16x8 a[4][4];
  const unsigned short* Ab = dsA + ((size_t)b*512 + (size_t)mt*64)*C_;
#pragma unroll
  for (int rf=0;rf<4;rf++)
#pragma unroll
    for (int s=0;s<4;s++)
      a[rf][s] = *(const bf16x8*)(Ab + (rf*16 + (l&15))*C_ + s*32 + (l>>4)*8);

  float den[4][4], sy[4][4], sx[4][4];
#pragma unroll
  for (int rf=0;rf<4;rf++)
#pragma unroll
    for (int j=0;j<4;j++){ den[rf][j]=0.f; sy[rf][j]=0.f; sx[rf][j]=0.f; }

  const unsigned short* Bb = d2nT + (size_t)b*HW_*C_ + ((size_t)(l&15))*C_ + (l>>4)*8;
  const int mc0 = nb*3200 + w*32;
  const int end = nb*3200 + 3200;

  auto loadB = [&](bf16x8 (&bf)[4][2], int mc){
#pragma unroll
    for (int s=0;s<4;s++)
#pragma unroll
      for (int cf=0;cf<2;cf++)
        bf[s][cf] = *(const bf16x8*)(Bb + (size_t)(mc + cf*16)*C_ + s*32);
  };

  auto compute = [&](bf16x8 (&bf)[4][2], int mc){
    f32x4 acc[4][2];
#pragma unroll
    for (int rf=0;rf<4;rf++)
#pragma unroll
      for (int cf=0;cf<2;cf++){ f32x4 z = {0.f,0.f,0.f,0.f}; acc[rf][cf] = z; }
#pragma unroll
    for (int s=0;s<4;s++)
#pragma unroll
      for (int cf=0;cf<2;cf++)
#pragma unroll
        for (int rf=0;rf<4;rf++)
          acc[rf][cf] = __builtin_amdgcn_mfma_f32_16x16x32_bf16(a[rf][s], bf[s][cf], acc[rf][cf], 0,0,0);
#pragma unroll
    for (int cf=0;cf<2;cf++){
      int mm = mc + cf*16 + (l&15);
      int yq = mm / 240;
      float yc = (float)yq, xc = (float)(mm - yq*240);
#pragma unroll
      for (int rf=0;rf<4;rf++)
#pragma unroll
        for (int j=0;j<4;j++){
          float e = exp2f(acc[rf][cf][j]);   // ci pre-scaled by log2e in dsA
          den[rf][j] += e;
          sy[rf][j]  += e*yc;
          sx[rf][j]  += e*xc;
        }
    }
  };

  bf16x8 bA[4][2], bB[4][2];
  loadB(bA, mc0);
#pragma unroll 1
  for (int mc = mc0; mc < end; mc += 256){
    if (mc+128 < end) loadB(bB, mc+128);
    compute(bA, mc);
    if (mc+128 < end){
      if (mc+256 < end) loadB(bA, mc+256);
      compute(bB, mc+128);
    }
  }

  // reduce over the 16 lanes sharing each row (xor 1,2,4,8)
#pragma unroll
  for (int rf=0;rf<4;rf++)
#pragma unroll
    for (int j=0;j<4;j++){
#pragma unroll
      for (int o=1;o<16;o<<=1){
        den[rf][j] += __shfl_xor(den[rf][j], o);
        sy[rf][j]  += __shfl_xor(sy[rf][j], o);
        sx[rf][j]  += __shfl_xor(sx[rf][j], o);
      }
    }
  if ((l&15)==0){
    int rbase = mt*64 + (l>>4)*4;
#pragma unroll
    for (int rf=0;rf<4;rf++)
#pragma unroll
      for (int j=0;j<4;j++){
        int row = rbase + rf*16 + j;
        if (row < NK_){
          float* p = pdacc + ((size_t)b*NK_ + row)*3;
          atomicAdd(p+0, den[rf][j]);
          atomicAdd(p+1, sy[rf][j]);
          atomicAdd(p+2, sx[rf][j]);
        }
      }
  }
}

// ---------------- K5: pd, dd, ss, sd, w_, per-keypoint moment RECORD (no atomics) ----------------
__global__ void k_fin(const float* __restrict__ desc2, const float* __restrict__ sc1,
                      const float* __restrict__ sc2, const float* __restrict__ ps,
                      const float* __restrict__ dsF, const float* __restrict__ pdacc,
                      float* __restrict__ rec){
  int wid = (blockIdx.x*blockDim.x + threadIdx.x) >> 6;
  int l = threadIdx.x & 63;
  if (wid >= B_*NK_) return;
  int b = wid / NK_;
  const float* pa = pdacc + (size_t)wid*3;
  float den = pa[0];
  float pdx = pa[1]/den;   // pd[...,0] = E[m//240], used as x in sampling (ref quirk)
  float pdy = pa[2]/den;
  Bil bl2 = bilin(pdx, pdy);
  const float* D2 = desc2 + (size_t)b*C_*HW_;
  float v[2];
#pragma unroll
  for (int t=0;t<2;t++){ int c = l + t*64; v[t] = bsample(D2 + (size_t)c*HW_, bl2); }
  float nrm = wave_sum64(v[0]*v[0] + v[1]*v[1]);
  float inv = 1.f/(sqrtf(nrm)+EPS_);
  float dot = 0.f;
#pragma unroll
  for (int t=0;t<2;t++){ int c = l + t*64; dot += dsF[(size_t)wid*C_ + c]*(v[t]*inv); }
  dot = wave_sum64(dot);
  float psx = ps[(size_t)wid*2+0], psy = ps[(size_t)wid*2+1];
  if (l==0){
    Bil bl1 = bilin(psx, psy);
    float ssv = bsample(sc1 + (size_t)b*HW_, bl1);
    float sdv = bsample(sc2 + (size_t)b*HW_, bl2);
    float wv = (dot + 1.f)*(ssv*sdv)*0.5f;
    float qsx = (psx - 119.5f)*0.25f, qsy = (119.5f - psy)*0.25f;
    float qdx = (pdx - 119.5f)*0.25f, qdy = (119.5f - pdy)*0.25f;
    float* R = rec + (size_t)wid*12;
    R[0] = wv;
    R[1] = wv*qsx;     R[2] = wv*qsy;
    R[3] = wv*qdx;     R[4] = wv*qdy;
    R[5] = wv*qsx*qdx; R[6] = wv*qsx*qdy;
    R[7] = wv*qsy*qdx; R[8] = wv*qsy*qdy;
  }
}

// ---------------- K6: reduce records + closed-form 2x2 Kabsch + loss ----------------
// 1 block, 4 waves; wave w owns batch w, lanes stride the 400 records.
__global__ __launch_bounds__(256) void k_pose(const float* __restrict__ rec,
                                              const float* __restrict__ ptrn,
                                              float* __restrict__ out){
  int w = threadIdx.x >> 6, l = threadIdx.x & 63;
  float s[9];
#pragma unroll
  for (int k=0;k<9;k++) s[k] = 0.f;
  for (int r = l; r < NK_; r += 64){
    const float* R = rec + ((size_t)(w*NK_ + r))*12;
#pragma unroll
    for (int k=0;k<9;k++) s[k] += R[k];
  }
#pragma unroll
  for (int k=0;k<9;k++) s[k] = wave_sum64(s[k]);
  __shared__ float lossw[4];
  if (l==0){
    float Wv=s[0], A0=s[1], A1=s[2], Bv0=s[3], Bv1=s[4];
    float M00=s[5], M01=s[6], M10=s[7], M11=s[8];
    float wsum = Wv + EPS_;
    float qsx=A0/wsum, qsy=A1/wsum, qdx=Bv0/wsum, qdy=Bv1/wsum;
    float S00 = M00 - qsx*Bv0 - A0*qdx + Wv*qsx*qdx;
    float S01 = M01 - qsx*Bv1 - A0*qdy + Wv*qsx*qdy;
    float S10 = M10 - qsy*Bv0 - A1*qdx + Wv*qsy*qdx;
    float S11 = M11 - qsy*Bv1 - A1*qdy + Wv*qsy*qdy;
    // R = argmax_{SO(2)} tr(R S) == V diag(1,det(VU^T)) U^T from SVD(S)
    float sv = S01 - S10, cv = S00 + S11;
    float hyp = sqrtf(sv*sv + cv*cv);
    float cs = cv/hyp, sn = sv/hyp;
    float tx = qdx - (cs*qsx - sn*qsy);
    float ty = qdy - (sn*qsx + cs*qsy);
    const float* P = ptrn + w*9;
    float dtx = P[2]-tx, dty = P[5]-ty;
    float lt = sqrtf(dtx*dtx + dty*dty);
    float a00 = P[0]*cs - P[1]*sn - 1.f;
    float a01 = P[0]*sn + P[1]*cs;
    float a10 = P[3]*cs - P[4]*sn;
    float a11 = P[3]*sn + P[4]*cs - 1.f;
    float lr = sqrtf(a00*a00 + a01*a01 + a10*a10 + a11*a11);
    lossw[w] = lt + 10.f*lr;
  }
  __syncthreads();
  if (threadIdx.x == 0)
    out[0] = (lossw[0] + lossw[1] + lossw[2] + lossw[3])*0.25f;
}

// ---------------- launch ----------------
extern "C" void kernel_launch(void* const* d_in, const int* in_sizes, int n_in,
                              void* d_out, int out_size, void* d_ws, size_t ws_size,
                              hipStream_t stream){
  const float* loc1  = (const float*)d_in[0];
  const float* sc1   = (const float*)d_in[1];
  const float* desc1 = (const float*)d_in[2];
  const float* sc2   = (const float*)d_in[3];
  const float* desc2 = (const float*)d_in[4];
  const float* ptrn  = (const float*)d_in[5];
  float* out = (float*)d_out;

  char* ws = (char*)d_ws;
  float* pdacc = (float*)(ws + 0);                        // 4*400*3 f32 = 19200 B
  float* ps    = (float*)(ws + 19456);                    // 4*400*2 f32 = 12800 B
  float* rec   = (float*)(ws + 32768);                    // 1600*12 f32 = 76800 B
  float* dsF   = (float*)(ws + 131072);                   // 4*400*128 f32 = 819200 B
  unsigned short* dsA  = (unsigned short*)(ws + 950272);  // 4*512*128 bf16 = 524288 B
  unsigned short* d2nT = (unsigned short*)(ws + 1474560); // 4*57600*128 bf16 = 58982400 B

  k_zero<<<(4800+255)/256, 256, 0, stream>>>(pdacc, 4800);
  k_kp  <<<400, 256, 0, stream>>>(loc1, ps);
  k_ds  <<<400, 256, 0, stream>>>(desc1, ps, dsF, dsA);
  k_d2nT<<<B_*H_*2, 256, 0, stream>>>(desc2, d2nT);
  k_flash<<<B_*NB2*MT2, 256, 0, stream>>>(dsA, d2nT, pdacc);
  k_fin <<<400, 256, 0, stream>>>(desc2, sc1, sc2, ps, dsF, pdacc, rec);
  k_pose<<<1, 256, 0, stream>>>(rec, ptrn, out);
}

// Round 11
// 354.010 us; speedup vs baseline: 1.5750x; 1.0240x over previous
//
#include <hip/hip_runtime.h>
#include <stdint.h>

#define B_ 4
#define C_ 128
#define H_ 240
#define W_ 240
#define HW_ (H_*W_)
#define NK_ 400
#define CELL_ 12
#define GW_ 20
#define EPS_ 1e-6f
#define LOG2E_ 1.4426950408889634f
#define NB2 36           // ns-blocks per (b,mt): 57600/36 = 1600 m per block
#define MT2 7            // 7 m-tiles of 64 rows cover 448 >= 400
#define GRID_FLASH (B_*NB2*MT2)   // 1008, divisible by 8 XCDs

typedef short bf16x8 __attribute__((ext_vector_type(8)));
typedef float f32x4 __attribute__((ext_vector_type(4)));

__device__ __forceinline__ float wave_sum64(float v){
#pragma unroll
  for (int o=32;o;o>>=1) v += __shfl_xor(v,o);
  return v;
}
__device__ __forceinline__ float wave_max64(float v){
#pragma unroll
  for (int o=32;o;o>>=1) v = fmaxf(v,__shfl_xor(v,o));
  return v;
}
__device__ __forceinline__ unsigned short f2bf(float f){
  uint32_t x = __float_as_uint(f);
  uint32_t r = (x + 0x7fffu + ((x>>16)&1u)) >> 16;
  return (unsigned short)r;
}

// ---------------- K0: zero accumulators ----------------
__global__ void k_zero(float* p, int n){
  int i = blockIdx.x*blockDim.x + threadIdx.x;
  if (i < n) p[i] = 0.f;
}

// ---------------- K1: spatial softmax keypoints ----------------
__global__ void k_kp(const float* __restrict__ loc, float* __restrict__ ps){
  int wid = (blockIdx.x*blockDim.x + threadIdx.x) >> 6;
  int l = threadIdx.x & 63;
  if (wid >= B_*NK_) return;
  int b = wid / NK_, n = wid % NK_;
  int gy = n / GW_, gx = n % GW_;
  const float* base = loc + (size_t)b*HW_ + (size_t)(gy*CELL_)*W_ + gx*CELL_;
  int d0 = l, d1 = l+64, d2 = l+128;
  float v0 = base[(d0/CELL_)*W_ + d0%CELL_];
  float v1 = base[(d1/CELL_)*W_ + d1%CELL_];
  float v2 = (l<16) ? base[(d2/CELL_)*W_ + d2%CELL_] : -3.4e38f;
  float m = wave_max64(fmaxf(fmaxf(v0,v1),v2));
  float e0 = expf(v0-m), e1 = expf(v1-m);
  float e2 = (l<16) ? expf(v2-m) : 0.f;
  float s  = e0+e1+e2;
  float sx = e0*(float)(d0%CELL_) + e1*(float)(d1%CELL_) + ((l<16)? e2*(float)(d2%CELL_) : 0.f);
  float sy = e0*(float)(d0/CELL_) + e1*(float)(d1/CELL_) + ((l<16)? e2*(float)(d2/CELL_) : 0.f);
  s = wave_sum64(s); sx = wave_sum64(sx); sy = wave_sum64(sy);
  if (l==0){
    // NOTE: reference's offs swaps grid axes: x-offset uses n//GW, y-offset uses n%GW
    ps[(size_t)wid*2+0] = sx/s + (float)((n/GW_)*CELL_);
    ps[(size_t)wid*2+1] = sy/s + (float)((n%GW_)*CELL_);
  }
}

// ---------------- bilinear helpers (exact reference semantics) ----------------
struct Bil { float wx, wy; int i00,i01,i10,i11; };
__device__ __forceinline__ Bil bilin(float px, float py){
  float x = fminf(fmaxf(px,0.f),(float)(W_-1));
  float y = fminf(fmaxf(py,0.f),(float)(H_-1));
  float x0f = floorf(x), y0f = floorf(y);
  Bil r; r.wx = x-x0f; r.wy = y-y0f;
  int x0 = (int)x0f, y0 = (int)y0f;
  int x1 = (x0+1 < W_) ? x0+1 : W_-1;
  int y1 = (y0+1 < H_) ? y0+1 : H_-1;
  r.i00 = y0*W_+x0; r.i01 = y0*W_+x1; r.i10 = y1*W_+x0; r.i11 = y1*W_+x1;
  return r;
}
__device__ __forceinline__ float bsample(const float* p, const Bil& bl){
  float v00=p[bl.i00], v01=p[bl.i01], v10=p[bl.i10], v11=p[bl.i11];
  return v00*(1.f-bl.wx)*(1.f-bl.wy) + v01*bl.wx*(1.f-bl.wy)
       + v10*(1.f-bl.wx)*bl.wy      + v11*bl.wx*bl.wy;
}

// ---------------- K2: ds = l2norm(bilinear(desc1, ps)); bf16 copy * LOG2E ----------------
__global__ void k_ds(const float* __restrict__ desc1, const float* __restrict__ ps,
                     float* __restrict__ dsF, unsigned short* __restrict__ dsA){
  int wid = (blockIdx.x*blockDim.x + threadIdx.x) >> 6;
  int l = threadIdx.x & 63;
  if (wid >= B_*NK_) return;
  int b = wid / NK_, n = wid % NK_;
  float px = ps[(size_t)wid*2+0], py = ps[(size_t)wid*2+1];
  Bil bl = bilin(px, py);
  const float* D = desc1 + (size_t)b*C_*HW_;
  float v[2];
#pragma unroll
  for (int t=0;t<2;t++){ int c = l + t*64; v[t] = bsample(D + (size_t)c*HW_, bl); }
  float nrm = wave_sum64(v[0]*v[0] + v[1]*v[1]);
  float inv = 1.f/(sqrtf(nrm)+EPS_);
#pragma unroll
  for (int t=0;t<2;t++){
    int c = l + t*64;
    float d = v[t]*inv;
    dsF[(size_t)wid*C_ + c] = d;
    dsA[((size_t)b*512 + n)*C_ + c] = f2bf(d*LOG2E_);
  }
}

// ---------------- K3: d2nT[b][m][c] = bf16(desc2[b][c][m] / (||row_w||+eps)) ----------------
// 64 channels per block (LDS 30 KB -> 5 blocks/CU), channel loop unrolled x8 for MLP.
__global__ __launch_bounds__(256) void k_d2nT(const float* __restrict__ desc2,
                                              unsigned short* __restrict__ d2nT){
  int blk = blockIdx.x;
  int chalf = blk & 1;
  int h = (blk >> 1) % H_;
  int b = blk / (2*H_);
  int w = threadIdx.x >> 6, l = threadIdx.x & 63;
  __shared__ unsigned short tile[64*W_];   // [c_local][w], 30720 B
  const float* src = desc2 + ((size_t)(b*C_ + chalf*64)*H_ + h)*W_;
#pragma unroll
  for (int i0=0;i0<16;i0+=8){
    float4 v[8];
#pragma unroll
    for (int u=0;u<8;u++){
      int cl = w*16 + i0 + u;
      v[u] = make_float4(0.f,0.f,0.f,0.f);
      if (l < 60) v[u] = *(const float4*)(src + (size_t)cl*HW_ + l*4);
    }
    float ss[8];
#pragma unroll
    for (int u=0;u<8;u++) ss[u] = v[u].x*v[u].x + v[u].y*v[u].y + v[u].z*v[u].z + v[u].w*v[u].w;
#pragma unroll
    for (int o=32;o;o>>=1)
#pragma unroll
      for (int u=0;u<8;u++) ss[u] += __shfl_xor(ss[u], o);
#pragma unroll
    for (int u=0;u<8;u++){
      int cl = w*16 + i0 + u;
      float inv = 1.f/(sqrtf(ss[u])+EPS_);
      if (l < 60){
        ushort4 o4; o4.x=f2bf(v[u].x*inv); o4.y=f2bf(v[u].y*inv);
        o4.z=f2bf(v[u].z*inv); o4.w=f2bf(v[u].w*inv);
        *(ushort4*)(&tile[cl*W_ + l*4]) = o4;
      }
    }
  }
  __syncthreads();
  int t = threadIdx.x;
  if (t < W_){
    unsigned short* dst = d2nT + ((size_t)b*HW_ + (size_t)h*W_ + t)*C_ + chalf*64;
#pragma unroll
    for (int q=0;q<8;q++){
      uint32_t u[4];
#pragma unroll
      for (int p=0;p<4;p++){
        unsigned short lo = tile[(q*8+2*p  )*W_ + t];
        unsigned short hi = tile[(q*8+2*p+1)*W_ + t];
        u[p] = (uint32_t)lo | ((uint32_t)hi<<16);
      }
      *(uint4*)(dst + q*8) = make_uint4(u[0],u[1],u[2],u[3]);
    }
  }
}

// ---------------- K4: fused GEMM + online softmax-expectation, LDS-free ----------------
// XCD-bijective swizzle: hw blocks on the same XCD (bid%8 equal) get a contiguous
// work range, so the 7 mt-siblings sharing a B-panel chunk hit one private L2.
__global__ __launch_bounds__(256, 2) void k_flash(const unsigned short* __restrict__ dsA,
                                                  const unsigned short* __restrict__ d2nT,
                                                  float* __restrict__ pdacc){
  int bid = blockIdx.x;
  int wg = (bid & 7)*(GRID_FLASH/8) + (bid >> 3);   // bijective: 1008 % 8 == 0
  int mt = wg % MT2;
  int g  = wg / MT2;
  int nb = g % NB2;
  int b  = g / NB2;
  int w = threadIdx.x >> 6, l = threadIdx.x & 63;

  // A fragments: row = mt*64 + rf*16 + (l&15), k = s*32 + (l>>4)*8 + j
  bf16x8 a[4][4];
  const unsigned short* Ab = dsA + ((size_t)b*512 + (size_t)mt*64)*C_;
#pragma unroll
  for (int rf=0;rf<4;rf++)
#pragma unroll
    for (int s=0;s<4;s++)
      a[rf][s] = *(const bf16x8*)(Ab + (rf*16 + (l&15))*C_ + s*32 + (l>>4)*8);

  float den[4][4], sy[4][4], sx[4][4];
#pragma unroll
  for (int rf=0;rf<4;rf++)
#pragma unroll
    for (int j=0;j<4;j++){ den[rf][j]=0.f; sy[rf][j]=0.f; sx[rf][j]=0.f; }

  const unsigned short* Bb = d2nT + (size_t)b*HW_*C_ + ((size_t)(l&15))*C_ + (l>>4)*8;
  const int mc0 = nb*1600 + w*32;
  const int end = nb*1600 + 1600;

  auto loadB = [&](bf16x8 (&bf)[4][2], int mc){
#pragma unroll
    for (int s=0;s<4;s++)
#pragma unroll
      for (int cf=0;cf<2;cf++)
        bf[s][cf] = *(const bf16x8*)(Bb + (size_t)(mc + cf*16)*C_ + s*32);
  };

  auto compute = [&](bf16x8 (&bf)[4][2], int mc){
    f32x4 acc[4][2];
#pragma unroll
    for (int rf=0;rf<4;rf++)
#pragma unroll
      for (int cf=0;cf<2;cf++){ f32x4 z = {0.f,0.f,0.f,0.f}; acc[rf][cf] = z; }
#pragma unroll
    for (int s=0;s<4;s++)
#pragma unroll
      for (int cf=0;cf<2;cf++)
#pragma unroll
        for (int rf=0;rf<4;rf++)
          acc[rf][cf] = __builtin_amdgcn_mfma_f32_16x16x32_bf16(a[rf][s], bf[s][cf], acc[rf][cf], 0,0,0);
#pragma unroll
    for (int cf=0;cf<2;cf++){
      int mm = mc + cf*16 + (l&15);
      int yq = mm / 240;
      float yc = (float)yq, xc = (float)(mm - yq*240);
#pragma unroll
      for (int rf=0;rf<4;rf++)
#pragma unroll
        for (int j=0;j<4;j++){
          float e = exp2f(acc[rf][cf][j]);   // ci pre-scaled by log2e in dsA
          den[rf][j] += e;
          sy[rf][j]  += e*yc;
          sx[rf][j]  += e*xc;
        }
    }
  };

  bf16x8 bA[4][2], bB[4][2];
  loadB(bA, mc0);
#pragma unroll 1
  for (int mc = mc0; mc < end; mc += 256){
    if (mc+128 < end) loadB(bB, mc+128);
    compute(bA, mc);
    if (mc+128 < end){
      if (mc+256 < end) loadB(bA, mc+256);
      compute(bB, mc+128);
    }
  }

  // reduce over the 16 lanes sharing each row (xor 1,2,4,8)
#pragma unroll
  for (int rf=0;rf<4;rf++)
#pragma unroll
    for (int j=0;j<4;j++){
#pragma unroll
      for (int o=1;o<16;o<<=1){
        den[rf][j] += __shfl_xor(den[rf][j], o);
        sy[rf][j]  += __shfl_xor(sy[rf][j], o);
        sx[rf][j]  += __shfl_xor(sx[rf][j], o);
      }
    }
  if ((l&15)==0){
    int rbase = mt*64 + (l>>4)*4;
#pragma unroll
    for (int rf=0;rf<4;rf++)
#pragma unroll
      for (int j=0;j<4;j++){
        int row = rbase + rf*16 + j;
        if (row < NK_){
          float* p = pdacc + ((size_t)b*NK_ + row)*3;
          atomicAdd(p+0, den[rf][j]);
          atomicAdd(p+1, sy[rf][j]);
          atomicAdd(p+2, sx[rf][j]);
        }
      }
  }
}

// ---------------- K5: pd, dd, ss, sd, w_, per-keypoint moment RECORD (no atomics) ----------------
__global__ void k_fin(const float* __restrict__ desc2, const float* __restrict__ sc1,
                      const float* __restrict__ sc2, const float* __restrict__ ps,
                      const float* __restrict__ dsF, const float* __restrict__ pdacc,
                      float* __restrict__ rec){
  int wid = (blockIdx.x*blockDim.x + threadIdx.x) >> 6;
  int l = threadIdx.x & 63;
  if (wid >= B_*NK_) return;
  int b = wid / NK_;
  const float* pa = pdacc + (size_t)wid*3;
  float den = pa[0];
  float pdx = pa[1]/den;   // pd[...,0] = E[m//240], used as x in sampling (ref quirk)
  float pdy = pa[2]/den;
  Bil bl2 = bilin(pdx, pdy);
  const float* D2 = desc2 + (size_t)b*C_*HW_;
  float v[2];
#pragma unroll
  for (int t=0;t<2;t++){ int c = l + t*64; v[t] = bsample(D2 + (size_t)c*HW_, bl2); }
  float nrm = wave_sum64(v[0]*v[0] + v[1]*v[1]);
  float inv = 1.f/(sqrtf(nrm)+EPS_);
  float dot = 0.f;
#pragma unroll
  for (int t=0;t<2;t++){ int c = l + t*64; dot += dsF[(size_t)wid*C_ + c]*(v[t]*inv); }
  dot = wave_sum64(dot);
  float psx = ps[(size_t)wid*2+0], psy = ps[(size_t)wid*2+1];
  if (l==0){
    Bil bl1 = bilin(psx, psy);
    float ssv = bsample(sc1 + (size_t)b*HW_, bl1);
    float sdv = bsample(sc2 + (size_t)b*HW_, bl2);
    float wv = (dot + 1.f)*(ssv*sdv)*0.5f;
    float qsx = (psx - 119.5f)*0.25f, qsy = (119.5f - psy)*0.25f;
    float qdx = (pdx - 119.5f)*0.25f, qdy = (119.5f - pdy)*0.25f;
    float* R = rec + (size_t)wid*12;
    R[0] = wv;
    R[1] = wv*qsx;     R[2] = wv*qsy;
    R[3] = wv*qdx;     R[4] = wv*qdy;
    R[5] = wv*qsx*qdx; R[6] = wv*qsx*qdy;
    R[7] = wv*qsy*qdx; R[8] = wv*qsy*qdy;
  }
}

// ---------------- K6: reduce records + closed-form 2x2 Kabsch + loss ----------------
// 1 block, 4 waves; wave w owns batch w, lanes stride the 400 records.
__global__ __launch_bounds__(256) void k_pose(const float* __restrict__ rec,
                                              const float* __restrict__ ptrn,
                                              float* __restrict__ out){
  int w = threadIdx.x >> 6, l = threadIdx.x & 63;
  float s[9];
#pragma unroll
  for (int k=0;k<9;k++) s[k] = 0.f;
  for (int r = l; r < NK_; r += 64){
    const float* R = rec + ((size_t)(w*NK_ + r))*12;
#pragma unroll
    for (int k=0;k<9;k++) s[k] += R[k];
  }
#pragma unroll
  for (int k=0;k<9;k++) s[k] = wave_sum64(s[k]);
  __shared__ float lossw[4];
  if (l==0){
    float Wv=s[0], A0=s[1], A1=s[2], Bv0=s[3], Bv1=s[4];
    float M00=s[5], M01=s[6], M10=s[7], M11=s[8];
    float wsum = Wv + EPS_;
    float qsx=A0/wsum, qsy=A1/wsum, qdx=Bv0/wsum, qdy=Bv1/wsum;
    float S00 = M00 - qsx*Bv0 - A0*qdx + Wv*qsx*qdx;
    float S01 = M01 - qsx*Bv1 - A0*qdy + Wv*qsx*qdy;
    float S10 = M10 - qsy*Bv0 - A1*qdx + Wv*qsy*qdx;
    float S11 = M11 - qsy*Bv1 - A1*qdy + Wv*qsy*qdy;
    // R = argmax_{SO(2)} tr(R S) == V diag(1,det(VU^T)) U^T from SVD(S)
    float sv = S01 - S10, cv = S00 + S11;
    float hyp = sqrtf(sv*sv + cv*cv);
    float cs = cv/hyp, sn = sv/hyp;
    float tx = qdx - (cs*qsx - sn*qsy);
    float ty = qdy - (sn*qsx + cs*qsy);
    const float* P = ptrn + w*9;
    float dtx = P[2]-tx, dty = P[5]-ty;
    float lt = sqrtf(dtx*dtx + dty*dty);
    float a00 = P[0]*cs - P[1]*sn - 1.f;
    float a01 = P[0]*sn + P[1]*cs;
    float a10 = P[3]*cs - P[4]*sn;
    float a11 = P[3]*sn + P[4]*cs - 1.f;
    float lr = sqrtf(a00*a00 + a01*a01 + a10*a10 + a11*a11);
    lossw[w] = lt + 10.f*lr;
  }
  __syncthreads();
  if (threadIdx.x == 0)
    out[0] = (lossw[0] + lossw[1] + lossw[2] + lossw[3])*0.25f;
}

// ---------------- launch ----------------
extern "C" void kernel_launch(void* const* d_in, const int* in_sizes, int n_in,
                              void* d_out, int out_size, void* d_ws, size_t ws_size,
                              hipStream_t stream){
  const float* loc1  = (const float*)d_in[0];
  const float* sc1   = (const float*)d_in[1];
  const float* desc1 = (const float*)d_in[2];
  const float* sc2   = (const float*)d_in[3];
  const float* desc2 = (const float*)d_in[4];
  const float* ptrn  = (const float*)d_in[5];
  float* out = (float*)d_out;

  char* ws = (char*)d_ws;
  float* pdacc = (float*)(ws + 0);                        // 4*400*3 f32 = 19200 B
  float* ps    = (float*)(ws + 19456);                    // 4*400*2 f32 = 12800 B
  float* rec   = (float*)(ws + 32768);                    // 1600*12 f32 = 76800 B
  float* dsF   = (float*)(ws + 131072);                   // 4*400*128 f32 = 819200 B
  unsigned short* dsA  = (unsigned short*)(ws + 950272);  // 4*512*128 bf16 = 524288 B
  unsigned short* d2nT = (unsigned short*)(ws + 1474560); // 4*57600*128 bf16 = 58982400 B

  k_zero<<<(4800+255)/256, 256, 0, stream>>>(pdacc, 4800);
  k_kp  <<<400, 256, 0, stream>>>(loc1, ps);
  k_ds  <<<400, 256, 0, stream>>>(desc1, ps, dsF, dsA);
  k_d2nT<<<B_*H_*2, 256, 0, stream>>>(desc2, d2nT);
  k_flash<<<GRID_FLASH, 256, 0, stream>>>(dsA, d2nT, pdacc);
  k_fin <<<400, 256, 0, stream>>>(desc2, sc1, sc2, ps, dsF, pdacc, rec);
  k_pose<<<1, 256, 0, stream>>>(rec, ptrn, out);
}